// Round 11
// baseline (163.175 us; speedup 1.0000x reference)
//
#include <hip/hip_runtime.h>
#include <math.h>

// Problem dims (fixed by reference)
#define BATCH 2048
#define GIN 128
#define GH 128
#define NE 8
#define XIN 512
#define UU 512

typedef __attribute__((ext_vector_type(8))) short short8;   // 8 bf16 in 4 VGPRs
typedef __attribute__((ext_vector_type(4))) float f32x4;

#define AS1 __attribute__((address_space(1)))
#define AS3 __attribute__((address_space(3)))

__device__ inline unsigned short f2bf(float f) {
    unsigned u = __float_as_uint(f);
    u += 0x7fffu + ((u >> 16) & 1u);
    return (unsigned short)(u >> 16);
}

__device__ inline float elu1(float x) { return x > 0.f ? x : (expf(x) - 1.f); }

// ---------------------------------------------------------------------------
// Fused pre-pass: blocks 0..511 run the gating MLP (4 batch rows each);
// blocks 512..7679 convert alpha pools + X fp32->bf16. (unchanged)
// ---------------------------------------------------------------------------
__global__ __launch_bounds__(256) void pre_kernel(
    const float* __restrict__ gin, const float* __restrict__ W0, const float* __restrict__ b0,
    const float* __restrict__ W1, const float* __restrict__ b1,
    const float* __restrict__ Wo, const float* __restrict__ bo,
    float* __restrict__ g,
    const float* __restrict__ a0, const float* __restrict__ a1, const float* __restrict__ a2,
    const float* __restrict__ xv, unsigned short* __restrict__ dst)
{
    __shared__ float xs[4][128];
    __shared__ float hs[4][128];
    __shared__ float ps[2][4][128];
    __shared__ float lp[8][4][8];
    __shared__ float ls[4][8];

    const int t = threadIdx.x;

    if (blockIdx.x >= 512) {
        // ---- convert part ----
        const long long vi = ((long long)(blockIdx.x - 512) * 256 + t) * 4;
        const int sel = (int)(vi >> 21);         // 0,1,2 = alpha pools; 3 = X
        const float* src = (sel == 0) ? a0 : (sel == 1) ? a1 : (sel == 2) ? a2 : xv;
        float4 v = *(const float4*)(src + (vi & ((1 << 21) - 1)));
        union { unsigned short us[4]; uint2 u2; } p;
        p.us[0] = f2bf(v.x); p.us[1] = f2bf(v.y); p.us[2] = f2bf(v.z); p.us[3] = f2bf(v.w);
        *(uint2*)(dst + vi) = p.u2;
        return;
    }

    // ---- gating part ----
    const int c = t & 127;
    const int h = t >> 7;
    const int row0 = blockIdx.x * 4;

    ((float*)xs)[t]       = gin[row0 * GIN + t];
    ((float*)xs)[t + 256] = gin[row0 * GIN + t + 256];
    __syncthreads();

    {   // layer 0
        float acc0 = 0.f, acc1 = 0.f, acc2 = 0.f, acc3 = 0.f;
        const float* Wc = W0 + c;
        #pragma unroll 8
        for (int i = h * 64; i < h * 64 + 64; ++i) {
            float w = Wc[i * GH];
            acc0 += xs[0][i] * w; acc1 += xs[1][i] * w;
            acc2 += xs[2][i] * w; acc3 += xs[3][i] * w;
        }
        ps[h][0][c] = acc0; ps[h][1][c] = acc1; ps[h][2][c] = acc2; ps[h][3][c] = acc3;
    }
    __syncthreads();
    {
        int o = t, r = o >> 7, cc = o & 127;
        hs[r][cc] = elu1(ps[0][r][cc] + ps[1][r][cc] + b0[cc]);
        o = t + 256; r = o >> 7; cc = o & 127;
        hs[r][cc] = elu1(ps[0][r][cc] + ps[1][r][cc] + b0[cc]);
    }
    __syncthreads();

    {   // layer 1
        float acc0 = 0.f, acc1 = 0.f, acc2 = 0.f, acc3 = 0.f;
        const float* Wc = W1 + c;
        #pragma unroll 8
        for (int i = h * 64; i < h * 64 + 64; ++i) {
            float w = Wc[i * GH];
            acc0 += hs[0][i] * w; acc1 += hs[1][i] * w;
            acc2 += hs[2][i] * w; acc3 += hs[3][i] * w;
        }
        ps[h][0][c] = acc0; ps[h][1][c] = acc1; ps[h][2][c] = acc2; ps[h][3][c] = acc3;
    }
    __syncthreads();
    {
        int o = t, r = o >> 7, cc = o & 127;
        xs[r][cc] = elu1(ps[0][r][cc] + ps[1][r][cc] + b1[cc]);
        o = t + 256; r = o >> 7; cc = o & 127;
        xs[r][cc] = elu1(ps[0][r][cc] + ps[1][r][cc] + b1[cc]);
    }
    __syncthreads();

    {   // output layer, 8-way k-split
        const int e = t & 7, r = (t >> 3) & 3, q = t >> 5;
        float s = 0.f;
        #pragma unroll
        for (int i = q * 16; i < q * 16 + 16; ++i) s += xs[r][i] * Wo[i * NE + e];
        lp[q][r][e] = s;
    }
    __syncthreads();
    if (t < 32) {
        const int r = t >> 3, e = t & 7;
        float s = bo[e];
        #pragma unroll
        for (int q = 0; q < 8; ++q) s += lp[q][r][e];
        ls[r][e] = s;
    }
    __syncthreads();
    if (t < 4) {
        float mx = ls[t][0];
        #pragma unroll
        for (int e = 1; e < 8; ++e) mx = fmaxf(mx, ls[t][e]);
        float s = 0.f, ex[8];
        #pragma unroll
        for (int e = 0; e < 8; ++e) { ex[e] = expf(ls[t][e] - mx); s += ex[e]; }
        float inv = 1.f / s;
        #pragma unroll
        for (int e = 0; e < 8; ++e) g[(row0 + t) * NE + e] = ex[e] * inv;
    }
}

// ---------------------------------------------------------------------------
// One fused MoE layer — DEEP-PREFETCH single-stage edition, ring-size FIXED.
// r10 FAILED (absmax 0.40) from a slot collision: prefetch slot (kk+4)&3
// == consume slot kk&3, so the in-loop LOADB overwrote the tile being fed
// to the MFMAs. Fix: 5-slot ring bb[5][4] (consume kk%5, prefetch (kk+4)%5
// — always distinct, prefetch distance 4 preserved). Everything else
// identical to r10:
//  - A-tile 64x512 (64 KB) staged FIRST via 16 global_load_lds, both-sides
//    swizzle; sched_barrier-pinned so vmcnt(16) PROVABLY = A landed
//    (16 newest outstanding = the 4 B prologue batches). One barrier.
//  - B: per-lane direct global->reg, depth 4 (16 loads in flight ~2000cy
//    cover > HBM latency; B is HBM-cold each iter, r6 FETCH=31MB).
//    Operand waits: compiler auto-waitcnt (register dataflow is tracked).
//  - 256 MFMA/wave between barriers; 3 barrier-crossings/layer.
// LDS 67 KB -> 2 blocks/CU. VGPR ~210 (cap 256 at 2 blocks/CU).
// Grid dim3(16,32)=512; linear bid%8 = n-tile%8 -> same-n blocks share XCD.
// ---------------------------------------------------------------------------
__global__ __launch_bounds__(256, 2) void moe_layer_kernel(
    const unsigned short* __restrict__ A,
    const unsigned short* __restrict__ Bw,
    const float* __restrict__ g,
    const float* __restrict__ beta,
    unsigned short* __restrict__ Xnext,
    float* __restrict__ out, int last)
{
    constexpr int K = XIN;
    __shared__ unsigned short As[64 * 512];     // 64 KB (red[] aliases later)
    __shared__ float gs[64][8];                 // 2 KB
    __shared__ float bt[8][32];                 // 1 KB

    const int t = threadIdx.x;
    const int n0 = blockIdx.x * 32;
    const int m0 = blockIdx.y * 64;
    const int wave = t >> 6, lane = t & 63;
    const int e0 = 2 * wave;
    const int fr = lane & 15;
    const int qb = (lane >> 4) * 16;            // 16B k-slot within a 64B kk-chunk

    ((float2*)gs)[t] = ((const float2*)(g + (size_t)m0 * NE))[t];
    bt[t >> 5][t & 31] = beta[(t >> 5) * UU + n0 + (t & 31)];

    f32x4 acc[2][4][2] = {};   // [expert-in-pair][m-frag][n-frag]

    // ---- B per-lane direct sources (4 frag rows per wave; row = 1KB) ----
    const unsigned short* b_ptr[4];
    #pragma unroll
    for (int ep = 0; ep < 2; ++ep)
        #pragma unroll
        for (int j = 0; j < 2; ++j)
            b_ptr[ep * 2 + j] =
                Bw + ((size_t)(e0 + ep) * UU + n0 + j * 16 + fr) * K + (lane >> 4) * 8;

    short8 bb[5][4];   // 5-slot ring, depth-4 prefetch (80 VGPR)

#define LOADB(slot, kk)                                                      \
    do {                                                                     \
        bb[slot][0] = *(const short8*)(b_ptr[0] + (kk) * 32);                \
        bb[slot][1] = *(const short8*)(b_ptr[1] + (kk) * 32);                \
        bb[slot][2] = *(const short8*)(b_ptr[2] + (kk) * 32);                \
        bb[slot][3] = *(const short8*)(b_ptr[3] + (kk) * 32);                \
    } while (0)

    // ---- stage the whole A-tile FIRST (64 rows x 512 cols, swizzled) ----
    // iteration it: wave w stages row it*4+w, lanes cover the full 1KB row
    // (64 x 16B segments, permuted within the row -> still 1KB-coalesced).
    #pragma unroll
    for (int it = 0; it < 16; ++it) {
        const int ldsb = it * 4096 + t * 16;
        const int row  = ldsb >> 10;
        const int colb = (ldsb & 1023) ^ ((row & 7) << 4);   // pre-swizzled src
        __builtin_amdgcn_global_load_lds(
            (const AS1 void*)(A + (size_t)(m0 + row) * K + (colb >> 1)),
            (AS3 void*)((char*)As + ldsb), 16, 0, 0);
    }
    __builtin_amdgcn_sched_barrier(0);   // pin: all 16 stage ops issued first

    // B prologue: batches kk=0..3 (16 loads) AFTER the stage ops
    LOADB(0, 0); LOADB(1, 1); LOADB(2, 2); LOADB(3, 3);
    __builtin_amdgcn_sched_barrier(0);   // pin: prologue after stage, before wait

    // 16 newest outstanding = the 4 B batches  =>  all 16 stage ops retired
    asm volatile("s_waitcnt vmcnt(16)" ::: "memory");
    __builtin_amdgcn_s_barrier();
    __builtin_amdgcn_sched_barrier(0);   // no LDS read hoisted above the barrier

    // ---- single fat compute phase: 16 kk, 256 MFMA/wave, no barriers ----
    // B-operand readiness enforced by compiler auto-waitcnt (register dep).
    // Ring: consume kk%5, prefetch (kk+4)%5 — never the same slot.
    #pragma unroll
    for (int kk = 0; kk < 16; ++kk) {
        if (kk + 4 < 16) LOADB((kk + 4) % 5, kk + 4);

        short8 af[4];
        #pragma unroll
        for (int i = 0; i < 4; ++i) {
            const int row = fr + i * 16;
            af[i] = *(const short8*)((const char*)As +
                    ((row * 1024 + kk * 64 + qb) ^ ((fr & 7) << 4)));
        }
        const int s = kk % 5;
        #pragma unroll
        for (int ep = 0; ep < 2; ++ep)
            #pragma unroll
            for (int i = 0; i < 4; ++i)
                #pragma unroll
                for (int j = 0; j < 2; ++j)
                    acc[ep][i][j] = __builtin_amdgcn_mfma_f32_16x16x32_bf16(
                        af[i], bb[s][ep * 2 + j], acc[ep][i][j], 0, 0, 0);
    }

    // ---- epilogue: blend + cross-wave sum via red[] aliased over As ----
    __syncthreads();                       // all af reads done -> safe to alias
    float* red = (float*)As;               // 4 waves x 64 x 32 f32 = 32 KB

    const int cl = lane & 15, rq = lane >> 4;
    #pragma unroll
    for (int i = 0; i < 4; ++i)
        #pragma unroll
        for (int j = 0; j < 2; ++j)
            #pragma unroll
            for (int r = 0; r < 4; ++r) {
                const int rl = i * 16 + rq * 4 + r;
                const int co = j * 16 + cl;
                const float v =
                    gs[rl][e0]     * (acc[0][i][j][r] + bt[e0][co]) +
                    gs[rl][e0 + 1] * (acc[1][i][j][r] + bt[e0 + 1][co]);
                red[wave * 2048 + rl * 32 + co] = v;
            }
    __syncthreads();

    {
        const int rl = t >> 2;
        const int c0 = (t & 3) * 8;
        float v[8];
        #pragma unroll
        for (int u = 0; u < 8; ++u) {
            const int idx = rl * 32 + c0 + u;
            v[u] = red[idx] + red[2048 + idx] + red[4096 + idx] + red[6144 + idx];
        }
        if (last) {
            float4 o0 = {v[0], v[1], v[2], v[3]};
            float4 o1 = {v[4], v[5], v[6], v[7]};
            float* op = out + (size_t)(m0 + rl) * UU + n0 + c0;
            *(float4*)op = o0;
            *(float4*)(op + 4) = o1;
        } else {
            union { unsigned short us[8]; short8 s8; } p;
            #pragma unroll
            for (int u = 0; u < 8; ++u) p.us[u] = f2bf(elu1(v[u]));
            *(short8*)(Xnext + (size_t)(m0 + rl) * UU + n0 + c0) = p.s8;
        }
    }
#undef LOADB
}

// ---------------------------------------------------------------------------
extern "C" void kernel_launch(void* const* d_in, const int* in_sizes, int n_in,
                              void* d_out, int out_size, void* d_ws, size_t ws_size,
                              hipStream_t stream)
{
    (void)in_sizes; (void)n_in; (void)out_size; (void)ws_size;
    const float* gin = (const float*)d_in[0];
    const float* xin = (const float*)d_in[1];
    const float* W0  = (const float*)d_in[2];
    const float* b0  = (const float*)d_in[3];
    const float* W1  = (const float*)d_in[4];
    const float* b1  = (const float*)d_in[5];
    const float* Wo  = (const float*)d_in[6];
    const float* bo  = (const float*)d_in[7];
    const float* alpha[3] = {(const float*)d_in[8],  (const float*)d_in[10], (const float*)d_in[12]};
    const float* beta[3]  = {(const float*)d_in[9],  (const float*)d_in[11], (const float*)d_in[13]};
    float* out = (float*)d_out;

    // ws layout (~16.8 MB total)
    char* ws = (char*)d_ws;
    float* g = (float*)ws;                                   // 64 KB
    size_t off = 65536;
    unsigned short* ab = (unsigned short*)(ws + off);        // 12.58 MB
    off += (size_t)3 * (1 << 21) * 2;
    unsigned short* Xb0 = (unsigned short*)(ws + off);       // 2.1 MB (contiguous after ab)
    off += (size_t)BATCH * XIN * 2;
    unsigned short* Xb1 = (unsigned short*)(ws + off);       // 2.1 MB
    off += (size_t)BATCH * XIN * 2;

    // fused gating + convert: 512 gating blocks + 7168 convert blocks
    pre_kernel<<<512 + 7168, 256, 0, stream>>>(
        gin, W0, b0, W1, b1, Wo, bo, g,
        alpha[0], alpha[1], alpha[2], xin, ab);

    // ping-pong X buffers
    unsigned short* Xsrc = Xb0;
    unsigned short* Xdst = Xb1;
    for (int l = 0; l < 3; ++l) {
        moe_layer_kernel<<<dim3(16, 32), 256, 0, stream>>>(
            Xsrc, ab + (size_t)l * (1 << 21), g, beta[l], Xdst, out, l == 2 ? 1 : 0);
        unsigned short* tmp = Xsrc; Xsrc = Xdst; Xdst = tmp;
    }
}